// Round 14
// baseline (446.276 us; speedup 1.0000x reference)
//
#include <hip/hip_runtime.h>
#include <hip/hip_bf16.h>
#include <stdint.h>

typedef __attribute__((ext_vector_type(8))) __bf16 bf16x8;
typedef __attribute__((ext_vector_type(4))) __bf16 bf16x4;
typedef __attribute__((ext_vector_type(4))) float  f32x4;

#define NTOK   8192
#define DMODEL 1024
#define HDIM   4096
#define NEXP   8

__device__ __forceinline__ void glds16(const void* g, void* l) {
  __builtin_amdgcn_global_load_lds(
      (const __attribute__((address_space(1))) uint32_t*)g,
      (__attribute__((address_space(3))) uint32_t*)l, 16, 0, 0);
}

#define WAITV(N) asm volatile("s_waitcnt vmcnt(" #N ")" ::: "memory")
#define SBAR()  do { __builtin_amdgcn_sched_barrier(0); \
                     __builtin_amdgcn_s_barrier();      \
                     __builtin_amdgcn_sched_barrier(0); } while (0)

// ------------------------------------------------------------------ utils
__global__ void zero_cnt_kernel(int* cnt) {
  if (threadIdx.x < NEXP) cnt[threadIdx.x] = 0;
}

// base[e+1] = base[e] + round256(cnt[e])   (256-row M-tiles)
__global__ void prefix_kernel(const int* __restrict__ cnt, int* __restrict__ base) {
  if (threadIdx.x == 0) {
    int b = 0;
    base[0] = 0;
    for (int e = 0; e < NEXP; ++e) {
      b += (cnt[e] + 255) & ~255;
      base[e + 1] = b;
    }
  }
}

// ------------------------------------------------------------------ bodies
__device__ void gate_body(int bid,
    const float* __restrict__ x, const float* __restrict__ gw,
    const float* __restrict__ gb, float* __restrict__ wgt,
    int* __restrict__ cnt, int* __restrict__ meta)
{
  const int lane = threadIdx.x & 63;
  const int wv   = threadIdx.x >> 6;
  const int t    = (bid << 2) + wv;
  const float* xp = x + (size_t)t * DMODEL;

  float acc[NEXP];
#pragma unroll
  for (int e = 0; e < NEXP; ++e) acc[e] = 0.f;

#pragma unroll
  for (int j = 0; j < DMODEL / 64; ++j) {
    const int d = (j << 6) + lane;
    const float xv = xp[d];
    const float4 g0 = *(const float4*)(gw + (size_t)d * NEXP);
    const float4 g1 = *(const float4*)(gw + (size_t)d * NEXP + 4);
    acc[0] = fmaf(xv, g0.x, acc[0]);
    acc[1] = fmaf(xv, g0.y, acc[1]);
    acc[2] = fmaf(xv, g0.z, acc[2]);
    acc[3] = fmaf(xv, g0.w, acc[3]);
    acc[4] = fmaf(xv, g1.x, acc[4]);
    acc[5] = fmaf(xv, g1.y, acc[5]);
    acc[6] = fmaf(xv, g1.z, acc[6]);
    acc[7] = fmaf(xv, g1.w, acc[7]);
  }
#pragma unroll
  for (int e = 0; e < NEXP; ++e) {
#pragma unroll
    for (int off = 32; off > 0; off >>= 1)
      acc[e] += __shfl_xor(acc[e], off, 64);
  }
  if (lane == 0) {
    float l[NEXP];
#pragma unroll
    for (int e = 0; e < NEXP; ++e) l[e] = acc[e] + gb[e];
    int i1 = 0; float m1 = l[0];
#pragma unroll
    for (int e = 1; e < NEXP; ++e) if (l[e] > m1) { m1 = l[e]; i1 = e; }
    int i2 = -1; float m2 = -3.402823466e38f;
#pragma unroll
    for (int e = 0; e < NEXP; ++e) if (e != i1 && l[e] > m2) { m2 = l[e]; i2 = e; }
    const int es = i1 > i2 ? i1 : i2;   // reference: last expert in loop wins
    float s = 0.f;
#pragma unroll
    for (int e = 0; e < NEXP; ++e) s += expf(l[e] - m1);
    const float w = expf(l[es] - m1) / s;
    wgt[t] = w;
    const int pos = atomicAdd(&cnt[es], 1);
    meta[t] = (es << 13) | pos;
  }
}

// pack_w, NO LDS: src [E][K][N] fp32 -> dst [E][N][K] bf16 (k-contig rows,
// same layout the GEMM stages from; swizzle stays at glds-source time).
// Thread owns output row n, k-range 32: 32 reads src[k0+j][n] — each load
// instruction = 64 lanes at consecutive n = contiguous 256B (coalesced).
// Write = 64B contiguous per thread (4 x 16B back-to-back fill whole lines
// via L2 write-combining). Zero LDS, zero barriers, zero bank conflicts.
template<int N, int K>
__device__ void packw_body(int bid, const float* __restrict__ src,
                           __bf16* __restrict__ dst)
{
  const int KT = K / 64, NP = N / 128;
  const int kt = bid % KT, np = (bid / KT) % NP, e = bid / (KT * NP);
  const int t = threadIdx.x;
  const int n  = np * 128 + (t & 127);
  const int k0 = kt * 64 + (t >> 7) * 32;

  const float* sp = src + (size_t)e * K * N + (size_t)k0 * N + n;
  float v[32];
#pragma unroll
  for (int j = 0; j < 32; ++j) v[j] = sp[(size_t)j * N];

  __bf16* dp = dst + ((size_t)e * N + n) * K + k0;
#pragma unroll
  for (int s = 0; s < 4; ++s) {
    bf16x8 o;
#pragma unroll
    for (int j = 0; j < 8; ++j) o[j] = (__bf16)v[s * 8 + j];
    *(bf16x8*)(dp + s * 8) = o;
  }
}

// fused A: gate (2048 blocks) + pack_w1 (4096) [+ pack_w2 (4096)]
__global__ __launch_bounds__(256) void fusedA_kernel(
    const float* __restrict__ x, const float* __restrict__ gw,
    const float* __restrict__ gb, float* __restrict__ wgt,
    int* __restrict__ cnt, int* __restrict__ meta,
    const float* __restrict__ w1, __bf16* __restrict__ w1p,
    const float* __restrict__ w2, __bf16* __restrict__ w2p)
{
  const int b = blockIdx.x;
  if (b < 2048)       gate_body(b, x, gw, gb, wgt, cnt, meta);
  else if (b < 6144)  packw_body<HDIM, DMODEL>(b - 2048, w1, w1p);
  else                packw_body<DMODEL, HDIM>(b - 6144, w2, w2p);
}

// standalone pack_w (serial fallback for w2)
template<int N, int K>
__global__ __launch_bounds__(256) void pack_w_kernel(
    const float* __restrict__ src, __bf16* __restrict__ dst)
{
  packw_body<N, K>(blockIdx.x, src, dst);
}

// -------------------------------------------------- pack x (sorted order)
// Pad rows keep stale bytes (finite bf16, harmless): GEMM1 writes 0 to hmat
// pad rows; GEMM2 only scatters gm<ce rows.
__global__ __launch_bounds__(256) void pack_x_kernel(
    const float* __restrict__ x, const float* __restrict__ wgt,
    const int* __restrict__ meta, const int* __restrict__ base,
    __bf16* __restrict__ xbf, int* __restrict__ sortmap)
{
  const int t = blockIdx.x * 2 + (threadIdx.x >> 7);
  const int l = threadIdx.x & 127;
  const int m = meta[t];
  const int es = m >> 13, pos = m & 8191;
  const int dst = base[es] + pos;
  const float w = wgt[t];
  const float4 a = *(const float4*)(x + (size_t)t * DMODEL + l * 8);
  const float4 b = *(const float4*)(x + (size_t)t * DMODEL + l * 8 + 4);
  bf16x8 o;
  o[0] = (__bf16)(a.x * w); o[1] = (__bf16)(a.y * w);
  o[2] = (__bf16)(a.z * w); o[3] = (__bf16)(a.w * w);
  o[4] = (__bf16)(b.x * w); o[5] = (__bf16)(b.y * w);
  o[6] = (__bf16)(b.z * w); o[7] = (__bf16)(b.w * w);
  *(bf16x8*)(xbf + (size_t)dst * DMODEL + l * 8) = o;
  if (l == 0) sortmap[dst] = t;
}

// ------------------------------------------------------------------ GEMM
// r7's verified core: 256x256 tile, 8 waves (2M x 4N, wave tile 128x64),
// BK=64, 2-buffer LDS (128KB), per K-tile { WAITV(0); barrier; stage next
// tile into other buffer; compute }. LDS rows 128B, granule phys = q^(row&7),
// swizzle at glds SOURCE (wave-uniform linear dest, m104 rule). Grid (np,m,e).
template<int KSTEPS, int ASTRIDE, int NOUT, bool RELU, bool SCATTER, typename OutT>
__global__ __launch_bounds__(512, 1) void moe_gemm256_kernel(
    const __bf16* __restrict__ Am, const __bf16* __restrict__ Bp,
    const float* __restrict__ bias, const int* __restrict__ cnt,
    const int* __restrict__ base, const int* __restrict__ sortmap,
    OutT* __restrict__ outp)
{
  const int e  = blockIdx.z;
  const int ce = cnt[e];
  const int rb = base[e];
  const int cep = base[e + 1] - rb;        // padded count (multiple of 256)
  const int m0 = blockIdx.y << 8;
  if (m0 >= cep) return;
  const int np = blockIdx.x, n0 = np << 8;

  const int tid = threadIdx.x, lane = tid & 63, wv = tid >> 6;
  const int wm = wv >> 2, wn = wv & 3;     // wave tile: rows wm*128, cols wn*64
  const int rl = lane & 15, sl = lane >> 4;

  __shared__ alignas(16) __bf16 lds[65536];   // 2 buffers x 64KB

  // per-lane staging SOURCES: 4 A + 4 B chunks (16B) per K-tile
  const __bf16* asrc[4];
  const __bf16* bsrc[4];
#pragma unroll
  for (int i = 0; i < 4; ++i) {
    const int c = (wv * 4 + i) * 64 + lane;       // chunk id 0..2047
    const int r = c >> 3, p = c & 7;              // tile row 0..255, granule
    const int koff = (p ^ (r & 7)) * 8;
    asrc[i] = Am + (size_t)(rb + m0 + r) * ASTRIDE + koff;
    bsrc[i] = Bp + ((size_t)(e * (NOUT / 128) + np * 2) * 128 + r) * ASTRIDE + koff;
  }

  auto stage = [&](int buf, int ks) {
    __bf16* Ad = lds + buf * 32768;               // wave-uniform dests
    __bf16* Bd = Ad + 16384;
#pragma unroll
    for (int i = 0; i < 4; ++i)
      glds16(asrc[i] + ks * 64, Ad + (wv * 4 + i) * 512);
#pragma unroll
    for (int i = 0; i < 4; ++i)
      glds16(bsrc[i] + ks * 64, Bd + (wv * 4 + i) * 512);
  };

  f32x4 acc[8][4] = {};

  stage(0, 0);
  for (int ks = 0; ks < KSTEPS; ++ks) {
    const int buf = ks & 1;
    WAITV(0);                    // this K-tile's stages (issued last iter) landed
    SBAR();                      // visible to all waves; prev buf fully read
    if (ks + 1 < KSTEPS) stage(buf ^ 1, ks + 1);

    const char* Ab = (const char*)lds + buf * 65536 + wm * 16384;
    const char* Bb = (const char*)lds + buf * 65536 + 32768 + (wn >> 1) * 16384;

#pragma unroll
    for (int kk = 0; kk < 2; ++kk) {
      bf16x8 af[8];
#pragma unroll
      for (int mf = 0; mf < 8; ++mf) {
        const int row = mf * 16 + rl;
        af[mf] = *(const bf16x8*)(Ab + row * 128 + (((kk * 4 + sl) ^ (row & 7)) << 4));
      }
#pragma unroll
      for (int nh = 0; nh < 2; ++nh) {
        bf16x8 bf2[2];
#pragma unroll
        for (int nf2 = 0; nf2 < 2; ++nf2) {
          const int row = (wn & 1) * 64 + nh * 32 + nf2 * 16 + rl;
          bf2[nf2] = *(const bf16x8*)(Bb + row * 128 + (((kk * 4 + sl) ^ (row & 7)) << 4));
        }
        __builtin_amdgcn_s_setprio(1);
#pragma unroll
        for (int mf = 0; mf < 8; ++mf)
#pragma unroll
          for (int nf2 = 0; nf2 < 2; ++nf2)
            acc[mf][nh * 2 + nf2] = __builtin_amdgcn_mfma_f32_16x16x32_bf16(
                af[mf], bf2[nf2], acc[mf][nh * 2 + nf2], 0, 0, 0);
        __builtin_amdgcn_s_setprio(0);
      }
    }
  }

  // epilogue: bias (+relu); sorted write or token scatter
  float bb[4];
#pragma unroll
  for (int nf = 0; nf < 4; ++nf)
    bb[nf] = bias[(size_t)e * NOUT + n0 + wn * 64 + nf * 16 + rl];

#pragma unroll
  for (int mf = 0; mf < 8; ++mf) {
#pragma unroll
    for (int j = 0; j < 4; ++j) {
      const int gm = m0 + wm * 128 + mf * 16 + sl * 4 + j;
      if constexpr (SCATTER) {
        if (gm < ce) {
          const int tok = sortmap[rb + gm];
          OutT* op = outp + (size_t)tok * NOUT + n0 + wn * 64;
#pragma unroll
          for (int nf = 0; nf < 4; ++nf)
            op[nf * 16 + rl] = (OutT)(acc[mf][nf][j] + bb[nf]);
        }
      } else {
        OutT* op = outp + (size_t)(rb + gm) * NOUT + n0 + wn * 64;
        const bool live = gm < ce;
#pragma unroll
        for (int nf = 0; nf < 4; ++nf) {
          float v = acc[mf][nf][j] + bb[nf];
          if constexpr (RELU) v = fmaxf(v, 0.f);
          op[nf * 16 + rl] = live ? (OutT)v : (OutT)0.f;
        }
      }
    }
  }
}

// ------------------------------------------------------------------ launch
extern "C" void kernel_launch(void* const* d_in, const int* in_sizes, int n_in,
                              void* d_out, int out_size, void* d_ws, size_t ws_size,
                              hipStream_t stream)
{
  const float* x  = (const float*)d_in[0];
  const float* gw = (const float*)d_in[1];
  const float* gb = (const float*)d_in[2];
  const float* w1 = (const float*)d_in[3];
  const float* b1 = (const float*)d_in[4];
  const float* w2 = (const float*)d_in[5];
  const float* b2 = (const float*)d_in[6];
  float* out = (float*)d_out;

  char* ws = (char*)d_ws;
  int*    cnt     = (int*)ws;                               // 32 B
  int*    base    = (int*)(ws + 256);                       // 9 ints
  int*    meta    = (int*)(ws + 4096);                      // 32 KB
  float*  wgt     = (float*)(ws + 40960);                   // 32 KB
  int*    sortmap = (int*)(ws + 81920);                     // 41 KB
  __bf16* xbf     = (__bf16*)(ws + ((size_t)1   << 20));    // <= 21 MB (10232 rows)
  __bf16* hmat    = (__bf16*)(ws + ((size_t)22  << 20));    // <= 84 MB
  __bf16* w1p     = (__bf16*)(ws + ((size_t)106 << 20));    // 64 MB

  const bool conc = ws_size >= ((size_t)235 << 20);

  zero_cnt_kernel<<<1, 64, 0, stream>>>(cnt);

  if (conc) {
    __bf16* w2p = (__bf16*)(ws + ((size_t)170 << 20));      // 64 MB (ends 234)
    // gate + pack_w1 + pack_w2 co-scheduled (independent streams of work)
    fusedA_kernel<<<10240, 256, 0, stream>>>(
        x, gw, gb, wgt, cnt, meta, w1, w1p, w2, w2p);
    prefix_kernel<<<1, 64, 0, stream>>>(cnt, base);
    pack_x_kernel<<<NTOK / 2, 256, 0, stream>>>(x, wgt, meta, base, xbf, sortmap);
    moe_gemm256_kernel<DMODEL / 64, DMODEL, HDIM, true, false, __bf16>
        <<<dim3(HDIM / 256, 40, NEXP), 512, 0, stream>>>(
            xbf, w1p, b1, cnt, base, sortmap, hmat);
    moe_gemm256_kernel<HDIM / 64, HDIM, DMODEL, false, true, float>
        <<<dim3(DMODEL / 256, 40, NEXP), 512, 0, stream>>>(
            hmat, w2p, b2, cnt, base, sortmap, out);
  } else {
    // serial fallback: pack w2 into w1p's space after GEMM1
    fusedA_kernel<<<6144, 256, 0, stream>>>(
        x, gw, gb, wgt, cnt, meta, w1, w1p, w2, w1p /*unused*/);
    prefix_kernel<<<1, 64, 0, stream>>>(cnt, base);
    pack_x_kernel<<<NTOK / 2, 256, 0, stream>>>(x, wgt, meta, base, xbf, sortmap);
    moe_gemm256_kernel<DMODEL / 64, DMODEL, HDIM, true, false, __bf16>
        <<<dim3(HDIM / 256, 40, NEXP), 512, 0, stream>>>(
            xbf, w1p, b1, cnt, base, sortmap, hmat);
    pack_w_kernel<DMODEL, HDIM><<<4096, 256, 0, stream>>>(w2, w1p);
    moe_gemm256_kernel<HDIM / 64, HDIM, DMODEL, false, true, float>
        <<<dim3(DMODEL / 256, 40, NEXP), 512, 0, stream>>>(
            hmat, w1p, b2, cnt, base, sortmap, out);
  }
}

// Round 15
// 395.342 us; speedup vs baseline: 1.1288x; 1.1288x over previous
//
#include <hip/hip_runtime.h>
#include <hip/hip_bf16.h>
#include <stdint.h>

typedef __attribute__((ext_vector_type(8))) __bf16 bf16x8;
typedef __attribute__((ext_vector_type(2))) __bf16 bf16x2;
typedef __attribute__((ext_vector_type(4))) float  f32x4;

#define NTOK   8192
#define DMODEL 1024
#define HDIM   4096
#define NEXP   8

__device__ __forceinline__ void glds16(const void* g, void* l) {
  __builtin_amdgcn_global_load_lds(
      (const __attribute__((address_space(1))) uint32_t*)g,
      (__attribute__((address_space(3))) uint32_t*)l, 16, 0, 0);
}

#define WAITV(N) asm volatile("s_waitcnt vmcnt(" #N ")" ::: "memory")
#define SBAR()  do { __builtin_amdgcn_sched_barrier(0); \
                     __builtin_amdgcn_s_barrier();      \
                     __builtin_amdgcn_sched_barrier(0); } while (0)

// ------------------------------------------------------------------ utils
__global__ void zero_cnt_kernel(int* cnt) {
  if (threadIdx.x < NEXP) cnt[threadIdx.x] = 0;
}

// base[e+1] = base[e] + round256(cnt[e])   (256-row M-tiles)
__global__ void prefix_kernel(const int* __restrict__ cnt, int* __restrict__ base) {
  if (threadIdx.x == 0) {
    int b = 0;
    base[0] = 0;
    for (int e = 0; e < NEXP; ++e) {
      b += (cnt[e] + 255) & ~255;
      base[e + 1] = b;
    }
  }
}

// ------------------------------------------------------------------ bodies
__device__ void gate_body(int bid,
    const float* __restrict__ x, const float* __restrict__ gw,
    const float* __restrict__ gb, float* __restrict__ wgt,
    int* __restrict__ cnt, int* __restrict__ meta)
{
  const int lane = threadIdx.x & 63;
  const int wv   = threadIdx.x >> 6;
  const int t    = (bid << 2) + wv;
  const float* xp = x + (size_t)t * DMODEL;

  float acc[NEXP];
#pragma unroll
  for (int e = 0; e < NEXP; ++e) acc[e] = 0.f;

#pragma unroll
  for (int j = 0; j < DMODEL / 64; ++j) {
    const int d = (j << 6) + lane;
    const float xv = xp[d];
    const float4 g0 = *(const float4*)(gw + (size_t)d * NEXP);
    const float4 g1 = *(const float4*)(gw + (size_t)d * NEXP + 4);
    acc[0] = fmaf(xv, g0.x, acc[0]);
    acc[1] = fmaf(xv, g0.y, acc[1]);
    acc[2] = fmaf(xv, g0.z, acc[2]);
    acc[3] = fmaf(xv, g0.w, acc[3]);
    acc[4] = fmaf(xv, g1.x, acc[4]);
    acc[5] = fmaf(xv, g1.y, acc[5]);
    acc[6] = fmaf(xv, g1.z, acc[6]);
    acc[7] = fmaf(xv, g1.w, acc[7]);
  }
#pragma unroll
  for (int e = 0; e < NEXP; ++e) {
#pragma unroll
    for (int off = 32; off > 0; off >>= 1)
      acc[e] += __shfl_xor(acc[e], off, 64);
  }
  if (lane == 0) {
    float l[NEXP];
#pragma unroll
    for (int e = 0; e < NEXP; ++e) l[e] = acc[e] + gb[e];
    int i1 = 0; float m1 = l[0];
#pragma unroll
    for (int e = 1; e < NEXP; ++e) if (l[e] > m1) { m1 = l[e]; i1 = e; }
    int i2 = -1; float m2 = -3.402823466e38f;
#pragma unroll
    for (int e = 0; e < NEXP; ++e) if (e != i1 && l[e] > m2) { m2 = l[e]; i2 = e; }
    const int es = i1 > i2 ? i1 : i2;   // reference: last expert in loop wins
    float s = 0.f;
#pragma unroll
    for (int e = 0; e < NEXP; ++e) s += expf(l[e] - m1);
    const float w = expf(l[es] - m1) / s;
    wgt[t] = w;
    const int pos = atomicAdd(&cnt[es], 1);
    meta[t] = (es << 13) | pos;
  }
}

// pack_w via LDS transpose, conflict-engineered:
// src [E][K][N] fp32 -> dst [E][N][K] bf16 (k-contig rows; GEMM layout).
// LDS layout: element (k,n) at  k*128 + ((n>>1 + 4*(k>>3)) & 63)*2 + (n&1).
//  - phase 1: one k-row per wave per instr (float2/lane = 512B contiguous
//    global read); phys_n2 is a permutation -> 2 lanes/bank LDS write (free).
//  - phase 2: lane l reads (k = 8*(l&7)+j, n = base + (l>>3)); bank =
//    (4*(l&7) + n>>1) % 32 -> all 32 banks, dword-sharing lanes broadcast
//    -> conflict-free. Writes: 8 threads share row n -> 128B full lines.
template<int N, int K>
__device__ void packw_body(int bid, const float* __restrict__ src,
                           __bf16* __restrict__ dst)
{
  const int KT = K / 64, NP = N / 128;
  const int kt = bid % KT, np = (bid / KT) % NP, e = bid / (KT * NP);
  const int t = threadIdx.x;
  __shared__ __bf16 sh[8192];   // 64 k x 128 n (rotated)

  const float* sp = src + (size_t)e * K * N + (size_t)(kt * 64) * N + np * 128;
  // phase 1: 16 iters; id = k*64 + n2
#pragma unroll
  for (int i = 0; i < 16; ++i) {
    const int id = i * 256 + t;             // 0..4095
    const int k = id >> 6, n2 = id & 63;
    const float2 v = *(const float2*)(sp + (size_t)k * N + n2 * 2);
    bf16x2 o; o[0] = (__bf16)v.x; o[1] = (__bf16)v.y;
    const int phys = (n2 + 4 * (k >> 3)) & 63;
    *(bf16x2*)&sh[k * 128 + phys * 2] = o;
  }
  __syncthreads();

  // phase 2: 4 iters; c = n*8 + ks8; 8 threads/row -> 128B line writes
  __bf16* dbase = dst + ((size_t)e * N + np * 128) * K + kt * 64;
#pragma unroll
  for (int i = 0; i < 4; ++i) {
    const int c = i * 256 + t;              // 0..1023
    const int n = c >> 3, ks8 = c & 7;
    const int nh = n >> 1, nl = n & 1;
    bf16x8 v;
#pragma unroll
    for (int j = 0; j < 8; ++j) {
      const int k = ks8 * 8 + j;
      v[j] = sh[k * 128 + (((nh + 4 * ks8) & 63) << 1) + nl];
    }
    *(bf16x8*)(dbase + (size_t)n * K + ks8 * 8) = v;
  }
}

// fused A: gate (2048 blocks) + pack_w1 (4096) [+ pack_w2 (4096)]
__global__ __launch_bounds__(256) void fusedA_kernel(
    const float* __restrict__ x, const float* __restrict__ gw,
    const float* __restrict__ gb, float* __restrict__ wgt,
    int* __restrict__ cnt, int* __restrict__ meta,
    const float* __restrict__ w1, __bf16* __restrict__ w1p,
    const float* __restrict__ w2, __bf16* __restrict__ w2p)
{
  const int b = blockIdx.x;
  if (b < 2048)       gate_body(b, x, gw, gb, wgt, cnt, meta);
  else if (b < 6144)  packw_body<HDIM, DMODEL>(b - 2048, w1, w1p);
  else                packw_body<DMODEL, HDIM>(b - 6144, w2, w2p);
}

// standalone pack_w (serial fallback for w2)
template<int N, int K>
__global__ __launch_bounds__(256) void pack_w_kernel(
    const float* __restrict__ src, __bf16* __restrict__ dst)
{
  packw_body<N, K>(blockIdx.x, src, dst);
}

// -------------------------------------------------- pack x (sorted order)
// Pad rows keep stale bytes (finite bf16, harmless): GEMM1 writes 0 to hmat
// pad rows; GEMM2 only scatters gm<ce rows.
__global__ __launch_bounds__(256) void pack_x_kernel(
    const float* __restrict__ x, const float* __restrict__ wgt,
    const int* __restrict__ meta, const int* __restrict__ base,
    __bf16* __restrict__ xbf, int* __restrict__ sortmap)
{
  const int t = blockIdx.x * 2 + (threadIdx.x >> 7);
  const int l = threadIdx.x & 127;
  const int m = meta[t];
  const int es = m >> 13, pos = m & 8191;
  const int dst = base[es] + pos;
  const float w = wgt[t];
  const float4 a = *(const float4*)(x + (size_t)t * DMODEL + l * 8);
  const float4 b = *(const float4*)(x + (size_t)t * DMODEL + l * 8 + 4);
  bf16x8 o;
  o[0] = (__bf16)(a.x * w); o[1] = (__bf16)(a.y * w);
  o[2] = (__bf16)(a.z * w); o[3] = (__bf16)(a.w * w);
  o[4] = (__bf16)(b.x * w); o[5] = (__bf16)(b.y * w);
  o[6] = (__bf16)(b.z * w); o[7] = (__bf16)(b.w * w);
  *(bf16x8*)(xbf + (size_t)dst * DMODEL + l * 8) = o;
  if (l == 0) sortmap[dst] = t;
}

// ------------------------------------------------------------------ GEMM
// r7's verified core: 256x256 tile, 8 waves (2M x 4N, wave tile 128x64),
// BK=64, 2-buffer LDS (128KB), per K-tile { WAITV(0); barrier; stage next
// tile into other buffer; compute }. LDS rows 128B, granule phys = q^(row&7),
// swizzle at glds SOURCE (wave-uniform linear dest, m104 rule). Grid (np,m,e).
template<int KSTEPS, int ASTRIDE, int NOUT, bool RELU, bool SCATTER, typename OutT>
__global__ __launch_bounds__(512, 1) void moe_gemm256_kernel(
    const __bf16* __restrict__ Am, const __bf16* __restrict__ Bp,
    const float* __restrict__ bias, const int* __restrict__ cnt,
    const int* __restrict__ base, const int* __restrict__ sortmap,
    OutT* __restrict__ outp)
{
  const int e  = blockIdx.z;
  const int ce = cnt[e];
  const int rb = base[e];
  const int cep = base[e + 1] - rb;        // padded count (multiple of 256)
  const int m0 = blockIdx.y << 8;
  if (m0 >= cep) return;
  const int np = blockIdx.x, n0 = np << 8;

  const int tid = threadIdx.x, lane = tid & 63, wv = tid >> 6;
  const int wm = wv >> 2, wn = wv & 3;     // wave tile: rows wm*128, cols wn*64
  const int rl = lane & 15, sl = lane >> 4;

  __shared__ alignas(16) __bf16 lds[65536];   // 2 buffers x 64KB

  // per-lane staging SOURCES: 4 A + 4 B chunks (16B) per K-tile
  const __bf16* asrc[4];
  const __bf16* bsrc[4];
#pragma unroll
  for (int i = 0; i < 4; ++i) {
    const int c = (wv * 4 + i) * 64 + lane;       // chunk id 0..2047
    const int r = c >> 3, p = c & 7;              // tile row 0..255, granule
    const int koff = (p ^ (r & 7)) * 8;
    asrc[i] = Am + (size_t)(rb + m0 + r) * ASTRIDE + koff;
    bsrc[i] = Bp + ((size_t)(e * (NOUT / 128) + np * 2) * 128 + r) * ASTRIDE + koff;
  }

  auto stage = [&](int buf, int ks) {
    __bf16* Ad = lds + buf * 32768;               // wave-uniform dests
    __bf16* Bd = Ad + 16384;
#pragma unroll
    for (int i = 0; i < 4; ++i)
      glds16(asrc[i] + ks * 64, Ad + (wv * 4 + i) * 512);
#pragma unroll
    for (int i = 0; i < 4; ++i)
      glds16(bsrc[i] + ks * 64, Bd + (wv * 4 + i) * 512);
  };

  f32x4 acc[8][4] = {};

  stage(0, 0);
  for (int ks = 0; ks < KSTEPS; ++ks) {
    const int buf = ks & 1;
    WAITV(0);                    // this K-tile's stages (issued last iter) landed
    SBAR();                      // visible to all waves; prev buf fully read
    if (ks + 1 < KSTEPS) stage(buf ^ 1, ks + 1);

    const char* Ab = (const char*)lds + buf * 65536 + wm * 16384;
    const char* Bb = (const char*)lds + buf * 65536 + 32768 + (wn >> 1) * 16384;

#pragma unroll
    for (int kk = 0; kk < 2; ++kk) {
      bf16x8 af[8];
#pragma unroll
      for (int mf = 0; mf < 8; ++mf) {
        const int row = mf * 16 + rl;
        af[mf] = *(const bf16x8*)(Ab + row * 128 + (((kk * 4 + sl) ^ (row & 7)) << 4));
      }
#pragma unroll
      for (int nh = 0; nh < 2; ++nh) {
        bf16x8 bf2[2];
#pragma unroll
        for (int nf2 = 0; nf2 < 2; ++nf2) {
          const int row = (wn & 1) * 64 + nh * 32 + nf2 * 16 + rl;
          bf2[nf2] = *(const bf16x8*)(Bb + row * 128 + (((kk * 4 + sl) ^ (row & 7)) << 4));
        }
        __builtin_amdgcn_s_setprio(1);
#pragma unroll
        for (int mf = 0; mf < 8; ++mf)
#pragma unroll
          for (int nf2 = 0; nf2 < 2; ++nf2)
            acc[mf][nh * 2 + nf2] = __builtin_amdgcn_mfma_f32_16x16x32_bf16(
                af[mf], bf2[nf2], acc[mf][nh * 2 + nf2], 0, 0, 0);
        __builtin_amdgcn_s_setprio(0);
      }
    }
  }

  // epilogue: bias (+relu); sorted write or token scatter
  float bb[4];
#pragma unroll
  for (int nf = 0; nf < 4; ++nf)
    bb[nf] = bias[(size_t)e * NOUT + n0 + wn * 64 + nf * 16 + rl];

#pragma unroll
  for (int mf = 0; mf < 8; ++mf) {
#pragma unroll
    for (int j = 0; j < 4; ++j) {
      const int gm = m0 + wm * 128 + mf * 16 + sl * 4 + j;
      if constexpr (SCATTER) {
        if (gm < ce) {
          const int tok = sortmap[rb + gm];
          OutT* op = outp + (size_t)tok * NOUT + n0 + wn * 64;
#pragma unroll
          for (int nf = 0; nf < 4; ++nf)
            op[nf * 16 + rl] = (OutT)(acc[mf][nf][j] + bb[nf]);
        }
      } else {
        OutT* op = outp + (size_t)(rb + gm) * NOUT + n0 + wn * 64;
        const bool live = gm < ce;
#pragma unroll
        for (int nf = 0; nf < 4; ++nf) {
          float v = acc[mf][nf][j] + bb[nf];
          if constexpr (RELU) v = fmaxf(v, 0.f);
          op[nf * 16 + rl] = live ? (OutT)v : (OutT)0.f;
        }
      }
    }
  }
}

// ------------------------------------------------------------------ launch
extern "C" void kernel_launch(void* const* d_in, const int* in_sizes, int n_in,
                              void* d_out, int out_size, void* d_ws, size_t ws_size,
                              hipStream_t stream)
{
  const float* x  = (const float*)d_in[0];
  const float* gw = (const float*)d_in[1];
  const float* gb = (const float*)d_in[2];
  const float* w1 = (const float*)d_in[3];
  const float* b1 = (const float*)d_in[4];
  const float* w2 = (const float*)d_in[5];
  const float* b2 = (const float*)d_in[6];
  float* out = (float*)d_out;

  char* ws = (char*)d_ws;
  int*    cnt     = (int*)ws;                               // 32 B
  int*    base    = (int*)(ws + 256);                       // 9 ints
  int*    meta    = (int*)(ws + 4096);                      // 32 KB
  float*  wgt     = (float*)(ws + 40960);                   // 32 KB
  int*    sortmap = (int*)(ws + 81920);                     // 41 KB
  __bf16* xbf     = (__bf16*)(ws + ((size_t)1   << 20));    // <= 21 MB (10232 rows)
  __bf16* hmat    = (__bf16*)(ws + ((size_t)22  << 20));    // <= 84 MB
  __bf16* w1p     = (__bf16*)(ws + ((size_t)106 << 20));    // 64 MB

  const bool conc = ws_size >= ((size_t)235 << 20);

  zero_cnt_kernel<<<1, 64, 0, stream>>>(cnt);

  if (conc) {
    __bf16* w2p = (__bf16*)(ws + ((size_t)170 << 20));      // 64 MB (ends 234)
    // gate + pack_w1 + pack_w2 co-scheduled (independent streams of work)
    fusedA_kernel<<<10240, 256, 0, stream>>>(
        x, gw, gb, wgt, cnt, meta, w1, w1p, w2, w2p);
    prefix_kernel<<<1, 64, 0, stream>>>(cnt, base);
    pack_x_kernel<<<NTOK / 2, 256, 0, stream>>>(x, wgt, meta, base, xbf, sortmap);
    moe_gemm256_kernel<DMODEL / 64, DMODEL, HDIM, true, false, __bf16>
        <<<dim3(HDIM / 256, 40, NEXP), 512, 0, stream>>>(
            xbf, w1p, b1, cnt, base, sortmap, hmat);
    moe_gemm256_kernel<HDIM / 64, HDIM, DMODEL, false, true, float>
        <<<dim3(DMODEL / 256, 40, NEXP), 512, 0, stream>>>(
            hmat, w2p, b2, cnt, base, sortmap, out);
  } else {
    // serial fallback: pack w2 into w1p's space after GEMM1
    fusedA_kernel<<<6144, 256, 0, stream>>>(
        x, gw, gb, wgt, cnt, meta, w1, w1p, w2, w1p /*unused*/);
    prefix_kernel<<<1, 64, 0, stream>>>(cnt, base);
    pack_x_kernel<<<NTOK / 2, 256, 0, stream>>>(x, wgt, meta, base, xbf, sortmap);
    moe_gemm256_kernel<DMODEL / 64, DMODEL, HDIM, true, false, __bf16>
        <<<dim3(HDIM / 256, 40, NEXP), 512, 0, stream>>>(
            xbf, w1p, b1, cnt, base, sortmap, hmat);
    pack_w_kernel<DMODEL, HDIM><<<4096, 256, 0, stream>>>(w2, w1p);
    moe_gemm256_kernel<HDIM / 64, HDIM, DMODEL, false, true, float>
        <<<dim3(DMODEL / 256, 40, NEXP), 512, 0, stream>>>(
            hmat, w1p, b2, cnt, base, sortmap, out);
  }
}

// Round 16
// 340.919 us; speedup vs baseline: 1.3090x; 1.1596x over previous
//
#include <hip/hip_runtime.h>
#include <hip/hip_bf16.h>
#include <stdint.h>

typedef __attribute__((ext_vector_type(8))) __bf16 bf16x8;
typedef __attribute__((ext_vector_type(2))) __bf16 bf16x2;
typedef __attribute__((ext_vector_type(4))) float  f32x4;

#define NTOK   8192
#define DMODEL 1024
#define HDIM   4096
#define NEXP   8

__device__ __forceinline__ void glds16(const void* g, void* l) {
  __builtin_amdgcn_global_load_lds(
      (const __attribute__((address_space(1))) uint32_t*)g,
      (__attribute__((address_space(3))) uint32_t*)l, 16, 0, 0);
}

#define WAITV(N) asm volatile("s_waitcnt vmcnt(" #N ")" ::: "memory")
#define SBAR()  do { __builtin_amdgcn_sched_barrier(0); \
                     __builtin_amdgcn_s_barrier();      \
                     __builtin_amdgcn_sched_barrier(0); } while (0)

// ------------------------------------------------------------------ utils
__global__ void zero_cnt_kernel(int* cnt) {
  if (threadIdx.x < NEXP) cnt[threadIdx.x] = 0;
}

// base[e+1] = base[e] + round256(cnt[e])   (256-row M-tiles)
__global__ void prefix_kernel(const int* __restrict__ cnt, int* __restrict__ base) {
  if (threadIdx.x == 0) {
    int b = 0;
    base[0] = 0;
    for (int e = 0; e < NEXP; ++e) {
      b += (cnt[e] + 255) & ~255;
      base[e + 1] = b;
    }
  }
}

// ------------------------------------------------------------------ bodies
__device__ void gate_body(int bid,
    const float* __restrict__ x, const float* __restrict__ gw,
    const float* __restrict__ gb, float* __restrict__ wgt,
    int* __restrict__ cnt, int* __restrict__ meta)
{
  const int lane = threadIdx.x & 63;
  const int wv   = threadIdx.x >> 6;
  const int t    = (bid << 2) + wv;
  const float* xp = x + (size_t)t * DMODEL;

  float acc[NEXP];
#pragma unroll
  for (int e = 0; e < NEXP; ++e) acc[e] = 0.f;

#pragma unroll
  for (int j = 0; j < DMODEL / 64; ++j) {
    const int d = (j << 6) + lane;
    const float xv = xp[d];
    const float4 g0 = *(const float4*)(gw + (size_t)d * NEXP);
    const float4 g1 = *(const float4*)(gw + (size_t)d * NEXP + 4);
    acc[0] = fmaf(xv, g0.x, acc[0]);
    acc[1] = fmaf(xv, g0.y, acc[1]);
    acc[2] = fmaf(xv, g0.z, acc[2]);
    acc[3] = fmaf(xv, g0.w, acc[3]);
    acc[4] = fmaf(xv, g1.x, acc[4]);
    acc[5] = fmaf(xv, g1.y, acc[5]);
    acc[6] = fmaf(xv, g1.z, acc[6]);
    acc[7] = fmaf(xv, g1.w, acc[7]);
  }
#pragma unroll
  for (int e = 0; e < NEXP; ++e) {
#pragma unroll
    for (int off = 32; off > 0; off >>= 1)
      acc[e] += __shfl_xor(acc[e], off, 64);
  }
  if (lane == 0) {
    float l[NEXP];
#pragma unroll
    for (int e = 0; e < NEXP; ++e) l[e] = acc[e] + gb[e];
    int i1 = 0; float m1 = l[0];
#pragma unroll
    for (int e = 1; e < NEXP; ++e) if (l[e] > m1) { m1 = l[e]; i1 = e; }
    int i2 = -1; float m2 = -3.402823466e38f;
#pragma unroll
    for (int e = 0; e < NEXP; ++e) if (e != i1 && l[e] > m2) { m2 = l[e]; i2 = e; }
    const int es = i1 > i2 ? i1 : i2;   // reference: last expert in loop wins
    float s = 0.f;
#pragma unroll
    for (int e = 0; e < NEXP; ++e) s += expf(l[e] - m1);
    const float w = expf(l[es] - m1) / s;
    wgt[t] = w;
    const int pos = atomicAdd(&cnt[es], 1);
    meta[t] = (es << 13) | pos;
  }
}

// pack_w via LDS transpose (r15 body, conflict-free verified):
// src [E][K][N] fp32 -> dst [E][N][K] bf16 (k-contig rows; GEMM layout).
// LDS: element (k,n) at k*128 + ((n>>1 + 4*(k>>3)) & 63)*2 + (n&1).
// Decode is NP-FASTEST then E then KT: consecutive pack ids hit different
// 512B column offsets and different experts -> HBM channel spread.
template<int N, int K>
__device__ void packw_body(int bid, const float* __restrict__ src,
                           __bf16* __restrict__ dst)
{
  const int KT = K / 64, NP = N / 128;
  const int np = bid % NP;
  const int e  = (bid / NP) % NEXP;
  const int kt = bid / (NP * NEXP);     // < KT
  const int t = threadIdx.x;
  __shared__ __bf16 sh[8192];   // 64 k x 128 n (rotated)

  const float* sp = src + (size_t)e * K * N + (size_t)(kt * 64) * N + np * 128;
  // phase 1: 16 iters; id = k*64 + n2 (one k-row per wave instr = 512B)
#pragma unroll
  for (int i = 0; i < 16; ++i) {
    const int id = i * 256 + t;             // 0..4095
    const int k = id >> 6, n2 = id & 63;
    const float2 v = *(const float2*)(sp + (size_t)k * N + n2 * 2);
    bf16x2 o; o[0] = (__bf16)v.x; o[1] = (__bf16)v.y;
    const int phys = (n2 + 4 * (k >> 3)) & 63;
    *(bf16x2*)&sh[k * 128 + phys * 2] = o;
  }
  __syncthreads();

  // phase 2: 4 iters; c = n*8 + ks8; 8 threads/row -> 128B line writes
  __bf16* dbase = dst + ((size_t)e * N + np * 128) * K + kt * 64;
#pragma unroll
  for (int i = 0; i < 4; ++i) {
    const int c = i * 256 + t;              // 0..1023
    const int n = c >> 3, ks8 = c & 7;
    const int nh = n >> 1, nl = n & 1;
    bf16x8 v;
#pragma unroll
    for (int j = 0; j < 8; ++j) {
      const int k = ks8 * 8 + j;
      v[j] = sh[k * 128 + (((nh + 4 * ks8) & 63) << 1) + nl];
    }
    *(bf16x8*)(dbase + (size_t)n * K + ks8 * 8) = v;
  }
}

// fused A, INTERLEAVED streams: bid%5 -> {gate, w1a, w1b, w2a, w2b} so
// latency-bound gate waves co-reside with BW-bound pack waves the whole
// dispatch (no serial phases). 2048 chunks x 5 = 10240 blocks.
__global__ __launch_bounds__(256) void fusedA_kernel(
    const float* __restrict__ x, const float* __restrict__ gw,
    const float* __restrict__ gb, float* __restrict__ wgt,
    int* __restrict__ cnt, int* __restrict__ meta,
    const float* __restrict__ w1, __bf16* __restrict__ w1p,
    const float* __restrict__ w2, __bf16* __restrict__ w2p)
{
  const int c = blockIdx.x / 5, sel = blockIdx.x % 5;
  if (sel == 0)       gate_body(c, x, gw, gb, wgt, cnt, meta);
  else if (sel <= 2)  packw_body<HDIM, DMODEL>(c * 2 + (sel - 1), w1, w1p);
  else                packw_body<DMODEL, HDIM>(c * 2 + (sel - 3), w2, w2p);
}

// fused A fallback (gate + w1 only): bid%3 -> {gate, w1a, w1b}, 6144 blocks
__global__ __launch_bounds__(256) void fusedA3_kernel(
    const float* __restrict__ x, const float* __restrict__ gw,
    const float* __restrict__ gb, float* __restrict__ wgt,
    int* __restrict__ cnt, int* __restrict__ meta,
    const float* __restrict__ w1, __bf16* __restrict__ w1p)
{
  const int c = blockIdx.x / 3, sel = blockIdx.x % 3;
  if (sel == 0) gate_body(c, x, gw, gb, wgt, cnt, meta);
  else          packw_body<HDIM, DMODEL>(c * 2 + (sel - 1), w1, w1p);
}

// standalone pack_w (serial fallback for w2)
template<int N, int K>
__global__ __launch_bounds__(256) void pack_w_kernel(
    const float* __restrict__ src, __bf16* __restrict__ dst)
{
  packw_body<N, K>(blockIdx.x, src, dst);
}

// -------------------------------------------------- pack x (sorted order)
// Pad rows keep stale bytes (finite bf16, harmless): GEMM1 writes 0 to hmat
// pad rows; GEMM2 only scatters gm<ce rows.
__global__ __launch_bounds__(256) void pack_x_kernel(
    const float* __restrict__ x, const float* __restrict__ wgt,
    const int* __restrict__ meta, const int* __restrict__ base,
    __bf16* __restrict__ xbf, int* __restrict__ sortmap)
{
  const int t = blockIdx.x * 2 + (threadIdx.x >> 7);
  const int l = threadIdx.x & 127;
  const int m = meta[t];
  const int es = m >> 13, pos = m & 8191;
  const int dst = base[es] + pos;
  const float w = wgt[t];
  const float4 a = *(const float4*)(x + (size_t)t * DMODEL + l * 8);
  const float4 b = *(const float4*)(x + (size_t)t * DMODEL + l * 8 + 4);
  bf16x8 o;
  o[0] = (__bf16)(a.x * w); o[1] = (__bf16)(a.y * w);
  o[2] = (__bf16)(a.z * w); o[3] = (__bf16)(a.w * w);
  o[4] = (__bf16)(b.x * w); o[5] = (__bf16)(b.y * w);
  o[6] = (__bf16)(b.z * w); o[7] = (__bf16)(b.w * w);
  *(bf16x8*)(xbf + (size_t)dst * DMODEL + l * 8) = o;
  if (l == 0) sortmap[dst] = t;
}

// ------------------------------------------------------------------ GEMM
// r7's verified core: 256x256 tile, 8 waves (2M x 4N, wave tile 128x64),
// BK=64, 2-buffer LDS (128KB), per K-tile { WAITV(0); barrier; stage next
// tile into other buffer; compute }. LDS rows 128B, granule phys = q^(row&7),
// swizzle at glds SOURCE (wave-uniform linear dest, m104 rule). Grid (np,m,e).
template<int KSTEPS, int ASTRIDE, int NOUT, bool RELU, bool SCATTER, typename OutT>
__global__ __launch_bounds__(512, 1) void moe_gemm256_kernel(
    const __bf16* __restrict__ Am, const __bf16* __restrict__ Bp,
    const float* __restrict__ bias, const int* __restrict__ cnt,
    const int* __restrict__ base, const int* __restrict__ sortmap,
    OutT* __restrict__ outp)
{
  const int e  = blockIdx.z;
  const int ce = cnt[e];
  const int rb = base[e];
  const int cep = base[e + 1] - rb;        // padded count (multiple of 256)
  const int m0 = blockIdx.y << 8;
  if (m0 >= cep) return;
  const int np = blockIdx.x, n0 = np << 8;

  const int tid = threadIdx.x, lane = tid & 63, wv = tid >> 6;
  const int wm = wv >> 2, wn = wv & 3;     // wave tile: rows wm*128, cols wn*64
  const int rl = lane & 15, sl = lane >> 4;

  __shared__ alignas(16) __bf16 lds[65536];   // 2 buffers x 64KB

  // per-lane staging SOURCES: 4 A + 4 B chunks (16B) per K-tile
  const __bf16* asrc[4];
  const __bf16* bsrc[4];
#pragma unroll
  for (int i = 0; i < 4; ++i) {
    const int c = (wv * 4 + i) * 64 + lane;       // chunk id 0..2047
    const int r = c >> 3, p = c & 7;              // tile row 0..255, granule
    const int koff = (p ^ (r & 7)) * 8;
    asrc[i] = Am + (size_t)(rb + m0 + r) * ASTRIDE + koff;
    bsrc[i] = Bp + ((size_t)(e * (NOUT / 128) + np * 2) * 128 + r) * ASTRIDE + koff;
  }

  auto stage = [&](int buf, int ks) {
    __bf16* Ad = lds + buf * 32768;               // wave-uniform dests
    __bf16* Bd = Ad + 16384;
#pragma unroll
    for (int i = 0; i < 4; ++i)
      glds16(asrc[i] + ks * 64, Ad + (wv * 4 + i) * 512);
#pragma unroll
    for (int i = 0; i < 4; ++i)
      glds16(bsrc[i] + ks * 64, Bd + (wv * 4 + i) * 512);
  };

  f32x4 acc[8][4] = {};

  stage(0, 0);
  for (int ks = 0; ks < KSTEPS; ++ks) {
    const int buf = ks & 1;
    WAITV(0);                    // this K-tile's stages (issued last iter) landed
    SBAR();                      // visible to all waves; prev buf fully read
    if (ks + 1 < KSTEPS) stage(buf ^ 1, ks + 1);

    const char* Ab = (const char*)lds + buf * 65536 + wm * 16384;
    const char* Bb = (const char*)lds + buf * 65536 + 32768 + (wn >> 1) * 16384;

#pragma unroll
    for (int kk = 0; kk < 2; ++kk) {
      bf16x8 af[8];
#pragma unroll
      for (int mf = 0; mf < 8; ++mf) {
        const int row = mf * 16 + rl;
        af[mf] = *(const bf16x8*)(Ab + row * 128 + (((kk * 4 + sl) ^ (row & 7)) << 4));
      }
#pragma unroll
      for (int nh = 0; nh < 2; ++nh) {
        bf16x8 bf2[2];
#pragma unroll
        for (int nf2 = 0; nf2 < 2; ++nf2) {
          const int row = (wn & 1) * 64 + nh * 32 + nf2 * 16 + rl;
          bf2[nf2] = *(const bf16x8*)(Bb + row * 128 + (((kk * 4 + sl) ^ (row & 7)) << 4));
        }
        __builtin_amdgcn_s_setprio(1);
#pragma unroll
        for (int mf = 0; mf < 8; ++mf)
#pragma unroll
          for (int nf2 = 0; nf2 < 2; ++nf2)
            acc[mf][nh * 2 + nf2] = __builtin_amdgcn_mfma_f32_16x16x32_bf16(
                af[mf], bf2[nf2], acc[mf][nh * 2 + nf2], 0, 0, 0);
        __builtin_amdgcn_s_setprio(0);
      }
    }
  }

  // epilogue: bias (+relu); sorted write or token scatter
  float bb[4];
#pragma unroll
  for (int nf = 0; nf < 4; ++nf)
    bb[nf] = bias[(size_t)e * NOUT + n0 + wn * 64 + nf * 16 + rl];

#pragma unroll
  for (int mf = 0; mf < 8; ++mf) {
#pragma unroll
    for (int j = 0; j < 4; ++j) {
      const int gm = m0 + wm * 128 + mf * 16 + sl * 4 + j;
      if constexpr (SCATTER) {
        if (gm < ce) {
          const int tok = sortmap[rb + gm];
          OutT* op = outp + (size_t)tok * NOUT + n0 + wn * 64;
#pragma unroll
          for (int nf = 0; nf < 4; ++nf)
            op[nf * 16 + rl] = (OutT)(acc[mf][nf][j] + bb[nf]);
        }
      } else {
        OutT* op = outp + (size_t)(rb + gm) * NOUT + n0 + wn * 64;
        const bool live = gm < ce;
#pragma unroll
        for (int nf = 0; nf < 4; ++nf) {
          float v = acc[mf][nf][j] + bb[nf];
          if constexpr (RELU) v = fmaxf(v, 0.f);
          op[nf * 16 + rl] = live ? (OutT)v : (OutT)0.f;
        }
      }
    }
  }
}

// ------------------------------------------------------------------ launch
extern "C" void kernel_launch(void* const* d_in, const int* in_sizes, int n_in,
                              void* d_out, int out_size, void* d_ws, size_t ws_size,
                              hipStream_t stream)
{
  const float* x  = (const float*)d_in[0];
  const float* gw = (const float*)d_in[1];
  const float* gb = (const float*)d_in[2];
  const float* w1 = (const float*)d_in[3];
  const float* b1 = (const float*)d_in[4];
  const float* w2 = (const float*)d_in[5];
  const float* b2 = (const float*)d_in[6];
  float* out = (float*)d_out;

  char* ws = (char*)d_ws;
  int*    cnt     = (int*)ws;                               // 32 B
  int*    base    = (int*)(ws + 256);                       // 9 ints
  int*    meta    = (int*)(ws + 4096);                      // 32 KB
  float*  wgt     = (float*)(ws + 40960);                   // 32 KB
  int*    sortmap = (int*)(ws + 81920);                     // 41 KB
  __bf16* xbf     = (__bf16*)(ws + ((size_t)1   << 20));    // <= 21 MB (10232 rows)
  __bf16* hmat    = (__bf16*)(ws + ((size_t)22  << 20));    // <= 84 MB
  __bf16* w1p     = (__bf16*)(ws + ((size_t)106 << 20));    // 64 MB

  const bool conc = ws_size >= ((size_t)235 << 20);

  zero_cnt_kernel<<<1, 64, 0, stream>>>(cnt);

  if (conc) {
    __bf16* w2p = (__bf16*)(ws + ((size_t)170 << 20));      // 64 MB (ends 234)
    // gate + pack_w1 + pack_w2, interleaved at bid granularity
    fusedA_kernel<<<10240, 256, 0, stream>>>(
        x, gw, gb, wgt, cnt, meta, w1, w1p, w2, w2p);
    prefix_kernel<<<1, 64, 0, stream>>>(cnt, base);
    pack_x_kernel<<<NTOK / 2, 256, 0, stream>>>(x, wgt, meta, base, xbf, sortmap);
    moe_gemm256_kernel<DMODEL / 64, DMODEL, HDIM, true, false, __bf16>
        <<<dim3(HDIM / 256, 40, NEXP), 512, 0, stream>>>(
            xbf, w1p, b1, cnt, base, sortmap, hmat);
    moe_gemm256_kernel<HDIM / 64, HDIM, DMODEL, false, true, float>
        <<<dim3(DMODEL / 256, 40, NEXP), 512, 0, stream>>>(
            hmat, w2p, b2, cnt, base, sortmap, out);
  } else {
    // serial fallback: pack w2 into w1p's space after GEMM1
    fusedA3_kernel<<<6144, 256, 0, stream>>>(
        x, gw, gb, wgt, cnt, meta, w1, w1p);
    prefix_kernel<<<1, 64, 0, stream>>>(cnt, base);
    pack_x_kernel<<<NTOK / 2, 256, 0, stream>>>(x, wgt, meta, base, xbf, sortmap);
    moe_gemm256_kernel<DMODEL / 64, DMODEL, HDIM, true, false, __bf16>
        <<<dim3(HDIM / 256, 40, NEXP), 512, 0, stream>>>(
            xbf, w1p, b1, cnt, base, sortmap, hmat);
    pack_w_kernel<DMODEL, HDIM><<<4096, 256, 0, stream>>>(w2, w1p);
    moe_gemm256_kernel<HDIM / 64, HDIM, DMODEL, false, true, float>
        <<<dim3(DMODEL / 256, 40, NEXP), 512, 0, stream>>>(
            hmat, w1p, b2, cnt, base, sortmap, out);
  }
}